// Round 5
// baseline (134.568 us; speedup 1.0000x reference)
//
#include <hip/hip_runtime.h>
#include <hip/hip_bf16.h>

// Eq2NetSet via bf16 MFMA (16x16x32, fp32 accum).
// Orientation: channels = M, pairs = N.  Per block: 64 triangle pairs (R5: was 128;
// smaller tiles -> 24.3 KB LDS -> 6 blocks/CU -> 6 waves/SIMD for latency hiding;
// R4 was 1.6 waves/SIMD effective, VALUBusy 18%, stall-bound).
//   L1: H1^T = W1^T (A) @ P^T (B),  K=64
//   L2: H2^T = W2^T @ H1^T,         K=128
//   L3: H3^T = W3^T @ H2^T,         K=128 -> relu -> weighted pair-sum
// Bias folded into MFMA acc init.  Paired bf16 RNE conversion.
// Per-block partials -> two-stage tree reduce -> decoder.

#define NB 4
#define NN 256
#define HD 128
#define TPB 514    // tiles per batch: 32896 pairs / 64

typedef __attribute__((ext_vector_type(8))) short bf16x8;
typedef __attribute__((ext_vector_type(4))) float f32x4;

// two fp32 -> packed bf16 pair (RNE), lo = a, hi = b
__device__ __forceinline__ unsigned rne2(float a, float b) {
    unsigned ua = __builtin_bit_cast(unsigned, a);
    unsigned ub = __builtin_bit_cast(unsigned, b);
    ua = ua + 0x7fff + ((ua >> 16) & 1);
    ub = ub + 0x7fff + ((ub >> 16) & 1);
    return (ua >> 16) | (ub & 0xffff0000u);
}

__device__ __forceinline__ short f2bf(float f) {
    unsigned u = __builtin_bit_cast(unsigned, f);
    u = (u + 0x7fff + ((u >> 16) & 1)) >> 16;
    return (short)u;
}

__device__ __forceinline__ void tri_ij(int t, int& i, int& j) {
    j = (int)((sqrtf(8.0f * (float)t + 1.0f) - 1.0f) * 0.5f);
    while (((j + 1) * (j + 2) >> 1) <= t) ++j;
    while (((j * (j + 1)) >> 1) > t) --j;
    i = t - ((j * (j + 1)) >> 1);
}

// pack W[fanin][128] into A-fragment-linear bf16: packed[(mt*KQ+kq)*64 + lane][j],
// value = W[kq*32 + (lane>>4)*8 + j][mt*16 + (lane&15)]
__device__ __forceinline__ void pack_w(const float* __restrict__ W, short* __restrict__ pw,
                                       int KQ, int u) {
    int l  = u & 63;
    int kq = (u >> 6) % KQ;
    int mt = (u >> 6) / KQ;
    int q = l >> 4, m = l & 15;
    int c = mt * 16 + m;
#pragma unroll
    for (int j = 0; j < 8; ++j) {
        int k = kq * 32 + q * 8 + j;
        pw[u * 8 + j] = f2bf(W[k * 128 + c]);
    }
}

__global__ void prep_kernel(const int* __restrict__ xcat,
                            const float* __restrict__ xfeat,
                            const float* __restrict__ emb,
                            const float* __restrict__ W1,
                            const float* __restrict__ W2,
                            const float* __restrict__ W3,
                            float* __restrict__ x,
                            short* __restrict__ pw1,
                            short* __restrict__ pw2,
                            short* __restrict__ pw3)
{
    int bid = blockIdx.x;
    int tid = threadIdx.x;
    if (bid < 256) {                       // build x[4][256][64] fp32
        int f = bid * 256 + tid;
        int d = f & 63;
        int nn = f >> 6;                   // b*256+n
        float v;
        if (d < 63) v = emb[xcat[nn] * 63 + d];
        else        v = xfeat[nn];
        x[f] = v;
    } else if (bid < 260) {                // W1: 8mt*2kq*64 = 1024 threads
        pack_w(W1, pw1, 2, (bid - 256) * 256 + tid);
    } else if (bid < 268) {                // W2: 8mt*4kq*64 = 2048
        pack_w(W2, pw2, 4, (bid - 260) * 256 + tid);
    } else {                               // W3
        pack_w(W3, pw3, 4, (bid - 268) * 256 + tid);
    }
}

__global__ __launch_bounds__(256, 6) void pair_mlp(
    const float* __restrict__ x,
    const short* __restrict__ pw1, const float* __restrict__ b1,
    const short* __restrict__ pw2, const float* __restrict__ b2,
    const short* __restrict__ pw3, const float* __restrict__ b3,
    float* __restrict__ partialOut)
{
    __shared__ short smP[64 * 64];     // 8 KB   P^T tile, row=pair, 64 bf16 (8 chunks)
    __shared__ short smH[64 * 128];    // 16 KB  H tile,   row=pair, 128 bf16 (16 chunks)
    __shared__ float smW[64];          // pair weights (1 diag / 2 off-diag)

    const int tid = threadIdx.x;
    const int l = tid & 63;
    const int w = __builtin_amdgcn_readfirstlane(tid >> 6);  // wave 0..3
    const int wm = w >> 1;             // channel half: mt in [wm*4, wm*4+4)
    const int wn = w & 1;              // pair half: pairs [wn*32, wn*32+32)
    const int q = l >> 4;
    const int m = l & 15;
    const int b = blockIdx.y;
    const int tbase = blockIdx.x * 64;           // triangle index base for this tile
    const float* xb = x + (b << 14);
    char* smPc = (char*)smP;
    char* smHc = (char*)smH;

    // ---- build P^T tile: 256 threads = 64 pairs x 4 quarter-rows ----
    {
        const int p = tid >> 2;
        const int qr = tid & 3;                  // 16-channel quarter
        int i, j;
        tri_ij(tbase + p, i, j);
        if (qr == 0) smW[p] = (i == j) ? 1.0f : 2.0f;
        const float4* xi4 = (const float4*)(xb + (i << 6) + qr * 16);
        const float4* xj4 = (const float4*)(xb + (j << 6) + qr * 16);
#pragma unroll
        for (int c = 0; c < 2; ++c) {
            float4 a0 = xi4[2 * c], a1 = xi4[2 * c + 1];
            float4 u0 = xj4[2 * c], u1 = xj4[2 * c + 1];
            uint4 s;
            s.x = rne2(a0.x * u0.x, a0.y * u0.y);
            s.y = rne2(a0.z * u0.z, a0.w * u0.w);
            s.z = rne2(a1.x * u1.x, a1.y * u1.y);
            s.w = rne2(a1.z * u1.z, a1.w * u1.w);
            int chunk = qr * 2 + c;
            int phys = chunk ^ (p & 7);
            *(uint4*)(smPc + p * 128 + phys * 16) = s;
        }
    }
    __syncthreads();

    f32x4 acc[4][2];

    // ---- L1: K=64, B from smP, acc init = b1 ----
#pragma unroll
    for (int mt = 0; mt < 4; ++mt) {
        float4 bv = *(const float4*)(b1 + (wm * 4 + mt) * 16 + q * 4);
        f32x4 init = {bv.x, bv.y, bv.z, bv.w};
        acc[mt][0] = init; acc[mt][1] = init;
    }

#pragma unroll
    for (int kq = 0; kq < 2; ++kq) {
        bf16x8 bfr[2], afr[4];
#pragma unroll
        for (int nt = 0; nt < 2; ++nt) {
            int pair = wn * 32 + nt * 16 + m;
            int phys = (kq * 4 + q) ^ (pair & 7);
            bfr[nt] = *(const bf16x8*)(smPc + pair * 128 + phys * 16);
        }
#pragma unroll
        for (int mt = 0; mt < 4; ++mt)
            afr[mt] = *(const bf16x8*)(pw1 + ((((wm * 4 + mt) * 2 + kq) * 64 + l) << 3));
#pragma unroll
        for (int mt = 0; mt < 4; ++mt)
#pragma unroll
            for (int nt = 0; nt < 2; ++nt)
                acc[mt][nt] = __builtin_amdgcn_mfma_f32_16x16x32_bf16(afr[mt], bfr[nt], acc[mt][nt], 0, 0, 0);
    }

    // epilogue L1 -> smH (relu + bf16 pack), swizzled 8B writes
#pragma unroll
    for (int mt = 0; mt < 4; ++mt) {
        int mtg = wm * 4 + mt;
#pragma unroll
        for (int nt = 0; nt < 2; ++nt) {
            int pair = wn * 32 + nt * 16 + m;
            uint2 sv;
            sv.x = rne2(fmaxf(acc[mt][nt][0], 0.f), fmaxf(acc[mt][nt][1], 0.f));
            sv.y = rne2(fmaxf(acc[mt][nt][2], 0.f), fmaxf(acc[mt][nt][3], 0.f));
            int chunk = mtg * 2 + (q >> 1);
            int phys = chunk ^ (pair & 15);
            *(uint2*)(smHc + pair * 256 + phys * 16 + (q & 1) * 8) = sv;
        }
    }
    __syncthreads();

    // ---- L2: K=128, B from smH (H1), acc init = b2 ----
#pragma unroll
    for (int mt = 0; mt < 4; ++mt) {
        float4 bv = *(const float4*)(b2 + (wm * 4 + mt) * 16 + q * 4);
        f32x4 init = {bv.x, bv.y, bv.z, bv.w};
        acc[mt][0] = init; acc[mt][1] = init;
    }

#pragma unroll
    for (int kq = 0; kq < 4; ++kq) {
        bf16x8 bfr[2], afr[4];
#pragma unroll
        for (int nt = 0; nt < 2; ++nt) {
            int pair = wn * 32 + nt * 16 + m;
            int phys = (kq * 4 + q) ^ (pair & 15);
            bfr[nt] = *(const bf16x8*)(smHc + pair * 256 + phys * 16);
        }
#pragma unroll
        for (int mt = 0; mt < 4; ++mt)
            afr[mt] = *(const bf16x8*)(pw2 + ((((wm * 4 + mt) * 4 + kq) * 64 + l) << 3));
#pragma unroll
        for (int mt = 0; mt < 4; ++mt)
#pragma unroll
            for (int nt = 0; nt < 2; ++nt)
                acc[mt][nt] = __builtin_amdgcn_mfma_f32_16x16x32_bf16(afr[mt], bfr[nt], acc[mt][nt], 0, 0, 0);
    }
    __syncthreads();   // all reads of H1 done before overwriting smH

    // epilogue L2 -> smH (H2)
#pragma unroll
    for (int mt = 0; mt < 4; ++mt) {
        int mtg = wm * 4 + mt;
#pragma unroll
        for (int nt = 0; nt < 2; ++nt) {
            int pair = wn * 32 + nt * 16 + m;
            uint2 sv;
            sv.x = rne2(fmaxf(acc[mt][nt][0], 0.f), fmaxf(acc[mt][nt][1], 0.f));
            sv.y = rne2(fmaxf(acc[mt][nt][2], 0.f), fmaxf(acc[mt][nt][3], 0.f));
            int chunk = mtg * 2 + (q >> 1);
            int phys = chunk ^ (pair & 15);
            *(uint2*)(smHc + pair * 256 + phys * 16 + (q & 1) * 8) = sv;
        }
    }
    __syncthreads();

    // ---- L3: K=128, B from smH (H2), acc init = b3 ----
#pragma unroll
    for (int mt = 0; mt < 4; ++mt) {
        float4 bv = *(const float4*)(b3 + (wm * 4 + mt) * 16 + q * 4);
        f32x4 init = {bv.x, bv.y, bv.z, bv.w};
        acc[mt][0] = init; acc[mt][1] = init;
    }

#pragma unroll
    for (int kq = 0; kq < 4; ++kq) {
        bf16x8 bfr[2], afr[4];
#pragma unroll
        for (int nt = 0; nt < 2; ++nt) {
            int pair = wn * 32 + nt * 16 + m;
            int phys = (kq * 4 + q) ^ (pair & 15);
            bfr[nt] = *(const bf16x8*)(smHc + pair * 256 + phys * 16);
        }
#pragma unroll
        for (int mt = 0; mt < 4; ++mt)
            afr[mt] = *(const bf16x8*)(pw3 + ((((wm * 4 + mt) * 4 + kq) * 64 + l) << 3));
#pragma unroll
        for (int mt = 0; mt < 4; ++mt)
#pragma unroll
            for (int nt = 0; nt < 2; ++nt)
                acc[mt][nt] = __builtin_amdgcn_mfma_f32_16x16x32_bf16(afr[mt], bfr[nt], acc[mt][nt], 0, 0, 0);
    }

    // ---- reduction: relu(h3) * pair-weight, sum over pairs -> LDS -> ws ----
    float wpv0 = smW[wn * 32 + m];
    float wpv1 = smW[wn * 32 + 16 + m];

    float* smPart = (float*)smP;   // 256 floats; smP dead since L1
#pragma unroll
    for (int mt = 0; mt < 4; ++mt) {
        int mtg = wm * 4 + mt;
        float vs[4];
#pragma unroll
        for (int r = 0; r < 4; ++r) {
            vs[r] = wpv0 * fmaxf(acc[mt][0][r], 0.f) + wpv1 * fmaxf(acc[mt][1][r], 0.f);
#pragma unroll
            for (int s = 1; s < 16; s <<= 1)
                vs[r] += __shfl_xor(vs[r], s, 64);
        }
        if (m == 0) {
            float* p = smPart + wn * HD + mtg * 16 + q * 4;
            p[0] = vs[0]; p[1] = vs[1]; p[2] = vs[2]; p[3] = vs[3];
        }
    }
    __syncthreads();

    if (tid < HD) {
        float v = smPart[tid] + smPart[HD + tid];
        partialOut[(b * TPB + blockIdx.x) * HD + tid] = v;   // coalesced 512B/block
    }
}

// stage-1 tree reduce: block (g,b) sums tiles [32g, 32g+32) -> partial2[b][17][128]
__global__ __launch_bounds__(128) void reduce1(const float* __restrict__ partial,
                                               float* __restrict__ partial2)
{
    const int ch = threadIdx.x;          // 128 threads
    const int g = blockIdx.x;            // 0..16
    const int b = blockIdx.y;
    const float* base = partial + (b * TPB + g * 32) * HD + ch;
    float s = 0.f;
#pragma unroll
    for (int t = 0; t < 32; ++t) {
        int tl = g * 32 + t;
        s += (tl < TPB) ? base[t * HD] : 0.f;
    }
    partial2[(b * 17 + g) * HD + ch] = s;
}

__global__ void reduce_decode(const float* __restrict__ partial2,
                              const float* __restrict__ D1, const float* __restrict__ c1,
                              const float* __restrict__ D2, const float* __restrict__ c2,
                              const float* __restrict__ D3, const float* __restrict__ c3,
                              float* __restrict__ out)
{
    __shared__ float red[2][HD];
    __shared__ float hb[HD];
    __shared__ float tb[HD];
    const int b = blockIdx.x;
    const int t = threadIdx.x;          // 256 threads
    const int ch = t & 127, hf = t >> 7;

    // sum 17 stage-1 partials per channel (split over 2 halves, unrolled)
    float s = 0.f;
#pragma unroll
    for (int g = 0; g < 9; ++g) {
        int tl = hf * 9 + g;
        s += (tl < 17) ? partial2[(b * 17 + tl) * HD + ch] : 0.f;
    }
    red[hf][ch] = s;
    __syncthreads();
    if (hf == 0)
        hb[ch] = fmaxf((red[0][ch] + red[1][ch]) * (1.0f / 65536.0f), 0.0f);
    __syncthreads();

    // dec layer 1 (split-k)
    float a = 0.f;
    for (int k = hf * 64; k < hf * 64 + 64; ++k)
        a = fmaf(hb[k], D1[(k << 7) + ch], a);
    red[hf][ch] = a;
    __syncthreads();
    if (hf == 0)
        tb[ch] = fmaxf(red[0][ch] + red[1][ch] + c1[ch], 0.0f);
    __syncthreads();

    // dec layer 2 (split-k)
    a = 0.f;
    for (int k = hf * 64; k < hf * 64 + 64; ++k)
        a = fmaf(tb[k], D2[(k << 7) + ch], a);
    red[hf][ch] = a;
    __syncthreads();
    if (hf == 0)
        hb[ch] = fmaxf(red[0][ch] + red[1][ch] + c2[ch], 0.0f);
    __syncthreads();

    // dec layer 3: out[b] = dot(hb, D3) + c3
    if (hf == 0) red[0][ch] = hb[ch] * D3[ch];
    __syncthreads();
    if (t < 64) {
        float r = red[0][t] + red[0][t + 64];
#pragma unroll
        for (int s2 = 1; s2 < 64; s2 <<= 1)
            r += __shfl_xor(r, s2, 64);
        if (t == 0) out[b] = r + c3[0];
    }
}

extern "C" void kernel_launch(void* const* d_in, const int* in_sizes, int n_in,
                              void* d_out, int out_size, void* d_ws, size_t ws_size,
                              hipStream_t stream)
{
    (void)in_sizes; (void)n_in; (void)out_size; (void)ws_size;

    const int*   xcat  = (const int*)  d_in[0];
    const float* xfeat = (const float*)d_in[1];
    const float* emb   = (const float*)d_in[2];
    const float* W1    = (const float*)d_in[3];
    const float* b1    = (const float*)d_in[4];
    const float* W2    = (const float*)d_in[5];
    const float* b2    = (const float*)d_in[6];
    const float* W3    = (const float*)d_in[7];
    const float* b3    = (const float*)d_in[8];
    const float* D1    = (const float*)d_in[9];
    const float* c1    = (const float*)d_in[10];
    const float* D2    = (const float*)d_in[11];
    const float* c2    = (const float*)d_in[12];
    const float* D3    = (const float*)d_in[13];
    const float* c3    = (const float*)d_in[14];
    float* out = (float*)d_out;

    float* x        = (float*)d_ws;                    // 65536 f
    short* pw1      = (short*)(x + NB * NN * 64);      // 8192 s
    short* pw2      = pw1 + 8 * 2 * 64 * 8;            // 16384 s
    short* pw3      = pw2 + 8 * 4 * 64 * 8;            // 16384 s
    float* partial  = (float*)(pw3 + 8 * 4 * 64 * 8);  // 4*514*128 f
    float* partial2 = partial + NB * TPB * HD;         // 4*17*128 f

    prep_kernel<<<276, 256, 0, stream>>>(xcat, xfeat, emb, W1, W2, W3,
                                         x, pw1, pw2, pw3);
    pair_mlp<<<dim3(TPB, NB), 256, 0, stream>>>(x, pw1, b1, pw2, b2, pw3, b3, partial);
    reduce1<<<dim3(17, NB), 128, 0, stream>>>(partial, partial2);
    reduce_decode<<<NB, 256, 0, stream>>>(partial2, D1, c1, D2, c2, D3, c3, out);
}

// Round 6
// 115.854 us; speedup vs baseline: 1.1615x; 1.1615x over previous
//
#include <hip/hip_runtime.h>
#include <hip/hip_bf16.h>

// Eq2NetSet via bf16 MFMA (16x16x32, fp32 accum).
// Orientation: channels = M, pairs = N.  Per block: 128 triangle pairs (R4 config —
// 64-pair tiles regressed: per-tile fixed costs doubled). R5 micro-opts kept:
// bias folded into acc init, paired rne2 bf16 pack, smW pair-weight cache.
//   L1: H1^T = W1^T (A) @ P^T (B),  K=64
//   L2: H2^T = W2^T @ H1^T,         K=128
//   L3: H3^T = W3^T @ H2^T,         K=128 -> relu -> weighted pair-sum
// Partials -> single fused reduce+decode kernel (one launch, no partial2 round-trip).

#define NB 4
#define NN 256
#define HD 128
#define TPB 257    // tiles per batch: 32896 pairs / 128

typedef __attribute__((ext_vector_type(8))) short bf16x8;
typedef __attribute__((ext_vector_type(4))) float f32x4;

// two fp32 -> packed bf16 pair (RNE), lo = a, hi = b
__device__ __forceinline__ unsigned rne2(float a, float b) {
    unsigned ua = __builtin_bit_cast(unsigned, a);
    unsigned ub = __builtin_bit_cast(unsigned, b);
    ua = ua + 0x7fff + ((ua >> 16) & 1);
    ub = ub + 0x7fff + ((ub >> 16) & 1);
    return (ua >> 16) | (ub & 0xffff0000u);
}

__device__ __forceinline__ short f2bf(float f) {
    unsigned u = __builtin_bit_cast(unsigned, f);
    u = (u + 0x7fff + ((u >> 16) & 1)) >> 16;
    return (short)u;
}

__device__ __forceinline__ void tri_ij(int t, int& i, int& j) {
    j = (int)((sqrtf(8.0f * (float)t + 1.0f) - 1.0f) * 0.5f);
    while (((j + 1) * (j + 2) >> 1) <= t) ++j;
    while (((j * (j + 1)) >> 1) > t) --j;
    i = t - ((j * (j + 1)) >> 1);
}

// pack W[fanin][128] into A-fragment-linear bf16: packed[(mt*KQ+kq)*64 + lane][j],
// value = W[kq*32 + (lane>>4)*8 + j][mt*16 + (lane&15)]
__device__ __forceinline__ void pack_w(const float* __restrict__ W, short* __restrict__ pw,
                                       int KQ, int u) {
    int l  = u & 63;
    int kq = (u >> 6) % KQ;
    int mt = (u >> 6) / KQ;
    int q = l >> 4, m = l & 15;
    int c = mt * 16 + m;
#pragma unroll
    for (int j = 0; j < 8; ++j) {
        int k = kq * 32 + q * 8 + j;
        pw[u * 8 + j] = f2bf(W[k * 128 + c]);
    }
}

__global__ void prep_kernel(const int* __restrict__ xcat,
                            const float* __restrict__ xfeat,
                            const float* __restrict__ emb,
                            const float* __restrict__ W1,
                            const float* __restrict__ W2,
                            const float* __restrict__ W3,
                            float* __restrict__ x,
                            short* __restrict__ pw1,
                            short* __restrict__ pw2,
                            short* __restrict__ pw3)
{
    int bid = blockIdx.x;
    int tid = threadIdx.x;
    if (bid < 256) {                       // build x[4][256][64] fp32
        int f = bid * 256 + tid;
        int d = f & 63;
        int nn = f >> 6;                   // b*256+n
        float v;
        if (d < 63) v = emb[xcat[nn] * 63 + d];
        else        v = xfeat[nn];
        x[f] = v;
    } else if (bid < 260) {                // W1: 8mt*2kq*64 = 1024 threads
        pack_w(W1, pw1, 2, (bid - 256) * 256 + tid);
    } else if (bid < 268) {                // W2: 8mt*4kq*64 = 2048
        pack_w(W2, pw2, 4, (bid - 260) * 256 + tid);
    } else {                               // W3
        pack_w(W3, pw3, 4, (bid - 268) * 256 + tid);
    }
}

__global__ __launch_bounds__(256, 3) void pair_mlp(
    const float* __restrict__ x,
    const short* __restrict__ pw1, const float* __restrict__ b1,
    const short* __restrict__ pw2, const float* __restrict__ b2,
    const short* __restrict__ pw3, const float* __restrict__ b3,
    float* __restrict__ partialOut)
{
    __shared__ short smP[128 * 64];    // 16 KB  P^T tile, row=pair, 64 bf16 (8 chunks)
    __shared__ short smH[128 * 128];   // 32 KB  H tile,   row=pair, 128 bf16 (16 chunks)
    __shared__ float smW[128];         // pair weights (1 diag / 2 off-diag)

    const int tid = threadIdx.x;
    const int l = tid & 63;
    const int w = __builtin_amdgcn_readfirstlane(tid >> 6);  // wave 0..3
    const int wm = w >> 1;             // channel half: mt in [wm*4, wm*4+4)
    const int wn = w & 1;              // pair half:    pairs [wn*64, wn*64+64)
    const int q = l >> 4;
    const int m = l & 15;
    const int b = blockIdx.y;
    const int tbase = blockIdx.x * 128;          // triangle index base for this tile
    const float* xb = x + (b << 14);
    char* smPc = (char*)smP;
    char* smHc = (char*)smH;

    // ---- build P^T tile: 256 threads, thread = (pair p = tid>>1, half = tid&1) ----
    {
        const int p = tid >> 1;
        const int half = tid & 1;
        int i, j;
        tri_ij(tbase + p, i, j);
        if (half == 0) smW[p] = (i == j) ? 1.0f : 2.0f;
        const float4* xi4 = (const float4*)(xb + (i << 6) + half * 32);
        const float4* xj4 = (const float4*)(xb + (j << 6) + half * 32);
#pragma unroll
        for (int c = 0; c < 4; ++c) {
            float4 a0 = xi4[2 * c], a1 = xi4[2 * c + 1];
            float4 u0 = xj4[2 * c], u1 = xj4[2 * c + 1];
            uint4 s;
            s.x = rne2(a0.x * u0.x, a0.y * u0.y);
            s.y = rne2(a0.z * u0.z, a0.w * u0.w);
            s.z = rne2(a1.x * u1.x, a1.y * u1.y);
            s.w = rne2(a1.z * u1.z, a1.w * u1.w);
            int chunk = half * 4 + c;
            int phys = chunk ^ (p & 7);
            *(uint4*)(smPc + p * 128 + phys * 16) = s;
        }
    }
    __syncthreads();

    f32x4 acc[4][4];

    // ---- L1: K=64, B from smP, acc init = b1 (bias fold) ----
#pragma unroll
    for (int mt = 0; mt < 4; ++mt) {
        float4 bv = *(const float4*)(b1 + (wm * 4 + mt) * 16 + q * 4);
        f32x4 init = {bv.x, bv.y, bv.z, bv.w};
#pragma unroll
        for (int nt = 0; nt < 4; ++nt) acc[mt][nt] = init;
    }

#pragma unroll
    for (int kq = 0; kq < 2; ++kq) {
        bf16x8 bfr[4], afr[4];
#pragma unroll
        for (int nt = 0; nt < 4; ++nt) {
            int pair = wn * 64 + nt * 16 + m;
            int phys = (kq * 4 + q) ^ (pair & 7);
            bfr[nt] = *(const bf16x8*)(smPc + pair * 128 + phys * 16);
        }
#pragma unroll
        for (int mt = 0; mt < 4; ++mt)
            afr[mt] = *(const bf16x8*)(pw1 + ((((wm * 4 + mt) * 2 + kq) * 64 + l) << 3));
#pragma unroll
        for (int mt = 0; mt < 4; ++mt)
#pragma unroll
            for (int nt = 0; nt < 4; ++nt)
                acc[mt][nt] = __builtin_amdgcn_mfma_f32_16x16x32_bf16(afr[mt], bfr[nt], acc[mt][nt], 0, 0, 0);
    }

    // epilogue L1 -> smH (relu + paired bf16 pack), swizzled 8B writes
#pragma unroll
    for (int mt = 0; mt < 4; ++mt) {
        int mtg = wm * 4 + mt;
#pragma unroll
        for (int nt = 0; nt < 4; ++nt) {
            int pair = wn * 64 + nt * 16 + m;
            uint2 sv;
            sv.x = rne2(fmaxf(acc[mt][nt][0], 0.f), fmaxf(acc[mt][nt][1], 0.f));
            sv.y = rne2(fmaxf(acc[mt][nt][2], 0.f), fmaxf(acc[mt][nt][3], 0.f));
            int chunk = mtg * 2 + (q >> 1);
            int phys = chunk ^ (pair & 15);
            *(uint2*)(smHc + pair * 256 + phys * 16 + (q & 1) * 8) = sv;
        }
    }
    __syncthreads();

    // ---- L2: K=128, B from smH (H1), acc init = b2 ----
#pragma unroll
    for (int mt = 0; mt < 4; ++mt) {
        float4 bv = *(const float4*)(b2 + (wm * 4 + mt) * 16 + q * 4);
        f32x4 init = {bv.x, bv.y, bv.z, bv.w};
#pragma unroll
        for (int nt = 0; nt < 4; ++nt) acc[mt][nt] = init;
    }

#pragma unroll
    for (int kq = 0; kq < 4; ++kq) {
        bf16x8 bfr[4], afr[4];
#pragma unroll
        for (int nt = 0; nt < 4; ++nt) {
            int pair = wn * 64 + nt * 16 + m;
            int phys = (kq * 4 + q) ^ (pair & 15);
            bfr[nt] = *(const bf16x8*)(smHc + pair * 256 + phys * 16);
        }
#pragma unroll
        for (int mt = 0; mt < 4; ++mt)
            afr[mt] = *(const bf16x8*)(pw2 + ((((wm * 4 + mt) * 4 + kq) * 64 + l) << 3));
#pragma unroll
        for (int mt = 0; mt < 4; ++mt)
#pragma unroll
            for (int nt = 0; nt < 4; ++nt)
                acc[mt][nt] = __builtin_amdgcn_mfma_f32_16x16x32_bf16(afr[mt], bfr[nt], acc[mt][nt], 0, 0, 0);
    }
    __syncthreads();   // all reads of H1 done before overwriting smH

    // epilogue L2 -> smH (H2)
#pragma unroll
    for (int mt = 0; mt < 4; ++mt) {
        int mtg = wm * 4 + mt;
#pragma unroll
        for (int nt = 0; nt < 4; ++nt) {
            int pair = wn * 64 + nt * 16 + m;
            uint2 sv;
            sv.x = rne2(fmaxf(acc[mt][nt][0], 0.f), fmaxf(acc[mt][nt][1], 0.f));
            sv.y = rne2(fmaxf(acc[mt][nt][2], 0.f), fmaxf(acc[mt][nt][3], 0.f));
            int chunk = mtg * 2 + (q >> 1);
            int phys = chunk ^ (pair & 15);
            *(uint2*)(smHc + pair * 256 + phys * 16 + (q & 1) * 8) = sv;
        }
    }
    __syncthreads();

    // ---- L3: K=128, B from smH (H2), acc init = b3 ----
#pragma unroll
    for (int mt = 0; mt < 4; ++mt) {
        float4 bv = *(const float4*)(b3 + (wm * 4 + mt) * 16 + q * 4);
        f32x4 init = {bv.x, bv.y, bv.z, bv.w};
#pragma unroll
        for (int nt = 0; nt < 4; ++nt) acc[mt][nt] = init;
    }

#pragma unroll
    for (int kq = 0; kq < 4; ++kq) {
        bf16x8 bfr[4], afr[4];
#pragma unroll
        for (int nt = 0; nt < 4; ++nt) {
            int pair = wn * 64 + nt * 16 + m;
            int phys = (kq * 4 + q) ^ (pair & 15);
            bfr[nt] = *(const bf16x8*)(smHc + pair * 256 + phys * 16);
        }
#pragma unroll
        for (int mt = 0; mt < 4; ++mt)
            afr[mt] = *(const bf16x8*)(pw3 + ((((wm * 4 + mt) * 4 + kq) * 64 + l) << 3));
#pragma unroll
        for (int mt = 0; mt < 4; ++mt)
#pragma unroll
            for (int nt = 0; nt < 4; ++nt)
                acc[mt][nt] = __builtin_amdgcn_mfma_f32_16x16x32_bf16(afr[mt], bfr[nt], acc[mt][nt], 0, 0, 0);
    }

    // ---- reduction: relu(h3) * pair-weight, sum over pairs -> LDS -> ws ----
    float wpv[4];
#pragma unroll
    for (int nt = 0; nt < 4; ++nt)
        wpv[nt] = smW[wn * 64 + nt * 16 + m];

    float* smPart = (float*)smP;   // 256 floats; smP dead since L1
#pragma unroll
    for (int mt = 0; mt < 4; ++mt) {
        int mtg = wm * 4 + mt;
        float vs[4];
#pragma unroll
        for (int r = 0; r < 4; ++r) {
            vs[r] = wpv[0] * fmaxf(acc[mt][0][r], 0.f) + wpv[1] * fmaxf(acc[mt][1][r], 0.f)
                  + wpv[2] * fmaxf(acc[mt][2][r], 0.f) + wpv[3] * fmaxf(acc[mt][3][r], 0.f);
#pragma unroll
            for (int s = 1; s < 16; s <<= 1)
                vs[r] += __shfl_xor(vs[r], s, 64);
        }
        if (m == 0) {
            float* p = smPart + wn * HD + mtg * 16 + q * 4;
            p[0] = vs[0]; p[1] = vs[1]; p[2] = vs[2]; p[3] = vs[3];
        }
    }
    __syncthreads();

    if (tid < HD) {
        float v = smPart[tid] + smPart[HD + tid];
        partialOut[(b * TPB + blockIdx.x) * HD + tid] = v;   // coalesced 512B/block
    }
}

// fused reduce + decoder: one block per batch, 1024 threads.
// Phase A: 8-way-sliced sum of TPB tile-partials per channel (independent unrolled loads).
// Phase B: 3-layer decoder on 256 threads (split-k halves).
__global__ __launch_bounds__(1024) void reduce_decode(
    const float* __restrict__ partial,
    const float* __restrict__ D1, const float* __restrict__ c1,
    const float* __restrict__ D2, const float* __restrict__ c2,
    const float* __restrict__ D3, const float* __restrict__ c3,
    float* __restrict__ out)
{
    __shared__ float red8[8][HD];
    __shared__ float red2[2][HD];
    __shared__ float hb[HD];
    __shared__ float tb[HD];
    const int b = blockIdx.x;
    const int t = threadIdx.x;          // 1024 threads
    const int ch = t & 127, sl = t >> 7;   // slice 0..7

    // Phase A: sum tiles tl = sl, sl+8, ... (unrolled x4 for load batching)
    {
        const float* base = partial + b * TPB * HD + ch;
        float s0 = 0.f, s1 = 0.f, s2 = 0.f, s3 = 0.f;
        int tl = sl;
        for (; tl + 32 <= TPB; tl += 32) {
            s0 += base[(tl     ) * HD];
            s1 += base[(tl +  8) * HD];
            s2 += base[(tl + 16) * HD];
            s3 += base[(tl + 24) * HD];
        }
        for (; tl < TPB; tl += 8) s0 += base[tl * HD];
        red8[sl][ch] = (s0 + s1) + (s2 + s3);
    }
    __syncthreads();
    if (sl == 0) {
        float v = ((red8[0][ch] + red8[1][ch]) + (red8[2][ch] + red8[3][ch]))
                + ((red8[4][ch] + red8[5][ch]) + (red8[6][ch] + red8[7][ch]));
        hb[ch] = fmaxf(v * (1.0f / 65536.0f), 0.0f);
    }
    __syncthreads();

    const int hf = sl & 1;   // for decode phases, threads t<256: hf = t>>7

    // dec layer 1 (split-k over 2 halves, 256 threads)
    if (t < 256) {
        float a = 0.f;
        for (int k = hf * 64; k < hf * 64 + 64; ++k)
            a = fmaf(hb[k], D1[(k << 7) + ch], a);
        red2[hf][ch] = a;
    }
    __syncthreads();
    if (t < 128)
        tb[ch] = fmaxf(red2[0][ch] + red2[1][ch] + c1[ch], 0.0f);
    __syncthreads();

    // dec layer 2
    if (t < 256) {
        float a = 0.f;
        for (int k = hf * 64; k < hf * 64 + 64; ++k)
            a = fmaf(tb[k], D2[(k << 7) + ch], a);
        red2[hf][ch] = a;
    }
    __syncthreads();
    if (t < 128)
        hb[ch] = fmaxf(red2[0][ch] + red2[1][ch] + c2[ch], 0.0f);
    __syncthreads();

    // dec layer 3: out[b] = dot(hb, D3) + c3
    if (t < 128) red2[0][ch] = hb[ch] * D3[ch];
    __syncthreads();
    if (t < 64) {
        float r = red2[0][t] + red2[0][t + 64];
#pragma unroll
        for (int s2 = 1; s2 < 64; s2 <<= 1)
            r += __shfl_xor(r, s2, 64);
        if (t == 0) out[b] = r + c3[0];
    }
}

extern "C" void kernel_launch(void* const* d_in, const int* in_sizes, int n_in,
                              void* d_out, int out_size, void* d_ws, size_t ws_size,
                              hipStream_t stream)
{
    (void)in_sizes; (void)n_in; (void)out_size; (void)ws_size;

    const int*   xcat  = (const int*)  d_in[0];
    const float* xfeat = (const float*)d_in[1];
    const float* emb   = (const float*)d_in[2];
    const float* W1    = (const float*)d_in[3];
    const float* b1    = (const float*)d_in[4];
    const float* W2    = (const float*)d_in[5];
    const float* b2    = (const float*)d_in[6];
    const float* W3    = (const float*)d_in[7];
    const float* b3    = (const float*)d_in[8];
    const float* D1    = (const float*)d_in[9];
    const float* c1    = (const float*)d_in[10];
    const float* D2    = (const float*)d_in[11];
    const float* c2    = (const float*)d_in[12];
    const float* D3    = (const float*)d_in[13];
    const float* c3    = (const float*)d_in[14];
    float* out = (float*)d_out;

    float* x       = (float*)d_ws;                    // 65536 f
    short* pw1     = (short*)(x + NB * NN * 64);      // 8192 s
    short* pw2     = pw1 + 8 * 2 * 64 * 8;            // 16384 s
    short* pw3     = pw2 + 8 * 4 * 64 * 8;            // 16384 s
    float* partial = (float*)(pw3 + 8 * 4 * 64 * 8);  // 4*257*128 f

    prep_kernel<<<276, 256, 0, stream>>>(xcat, xfeat, emb, W1, W2, W3,
                                         x, pw1, pw2, pw3);
    pair_mlp<<<dim3(TPB, NB), 256, 0, stream>>>(x, pw1, b1, pw2, b2, pw3, b3, partial);
    reduce_decode<<<NB, 1024, 0, stream>>>(partial, D1, c1, D2, c2, D3, c3, out);
}